// Round 6
// baseline (6181.036 us; speedup 1.0000x reference)
//
#include <hip/hip_runtime.h>

// ManualLSTM: B=32, S=2048, I=256, H=512.
// Round-8: r7 (5.38ms) + three critical-path cuts:
//   (1) EARLY PULLS: speculative h pulls for step t+1 issued at the END of
//       step t's cell phase (right after own publish). Symmetric schedule =>
//       own-publish time ~ peer-publish time, so pull flight overlaps the
//       visibility window and the first tag check usually succeeds -- removes
//       the ~1 extra reload round (~700cy MALL RT) per step that loop-top
//       issue caused (first check landed only ~250cy after issue).
//   (2) XCVT+XLOAD moved to spin-exit (before HSTEPs): the x(t+2) HBM load is
//       ~1000+cy old at the NEXT spin's vmcnt(0) (was ~500-800 => 100-400cy
//       stall inside the spin).
//   (3) pgat: stride-128 XOR swizzle col ^= ((row&3)^((row>>2)&3))<<3.
//       Writes: key varies with lq (row>>2) => exact 2-way (free, m136).
//       Reads: key varies with bl&3 (row&3) within a wave; float2 reads land
//       at the 4-cycle b64 minimum (conflict-free) and halve read count.
//       (r7's 133-pad fixed reads but made the 32 writes ~3-way: counter
//       DOUBLED to 3.36e7. Wi[128][264] verified conflict-free; untouched.)
// Structure (unchanged, correctness-proven r6/r7): 2 groups x 16 batches;
// 16 WGs/group, full W_hh in VGPRs (128/lane); group-local tagged-word
// exchange ((tag<<16)|bf16(h), 8B sc0 sc1 stores; slot parity;
// publish-certifies-consumption induction covers slot WAR -- early pulls only
// add EARLIER reads, and a peer cannot publish tag t+3 into the slot until we
// publish t+1, which follows our spin-exit, so no ABA and no deadlock).

#define BB 32
#define SS 2048
#define II 256
#define HH 512
#define NT 256
#define SLOTW 8192              // words per group-slot: 16 batches x 512 cols

typedef __bf16 bf16x8 __attribute__((ext_vector_type(8)));
typedef float f32x4 __attribute__((ext_vector_type(4)));
typedef unsigned u32x4 __attribute__((ext_vector_type(4)));
typedef unsigned u32x2 __attribute__((ext_vector_type(2)));

union BFU { __bf16 h; unsigned short u; };
union FRG { unsigned d[4]; bf16x8 b; };

__device__ __forceinline__ bf16x8 cvt8(float4 a, float4 b) {
  bf16x8 r;
  r[0] = (__bf16)a.x; r[1] = (__bf16)a.y; r[2] = (__bf16)a.z; r[3] = (__bf16)a.w;
  r[4] = (__bf16)b.x; r[5] = (__bf16)b.y; r[6] = (__bf16)b.z; r[7] = (__bf16)b.w;
  return r;
}

__global__ __launch_bounds__(256, 1) void lstm_init(
    const float* __restrict__ h0, unsigned* __restrict__ hw) {
  int i = blockIdx.x * 256 + threadIdx.x;   // 0..16383 = B*H
  const int b = i >> 9, col = i & 511;
  const int G = b >> 4, bl = b & 15;
  BFU cv; cv.h = (__bf16)h0[i];
  hw[(G * 2 + 0) * SLOTW + bl * 512 + col] = (unsigned)cv.u;  // slot0: tag 0|h0
  hw[(G * 2 + 1) * SLOTW + bl * 512 + col] = 0xFFFF0000u;     // slot1: sentinel
}

__global__ __launch_bounds__(256, 1) void lstm_persistent(
    const float* __restrict__ x, const float* __restrict__ c0,
    const float* __restrict__ W_ih, const float* __restrict__ b_ih,
    const float* __restrict__ W_hh, float* __restrict__ out,
    unsigned* __restrict__ hw) {
  __shared__ __bf16 Wi[128][264];        // x-part weights (conflict-free)
  __shared__ float pgat[2][4][16][128];  // dbl-buffered partials, XOR-swizzled

  const int g = blockIdx.x;
  const int wgj = g & 15;              // col-slice within group
  const int grp = g >> 4;              // batch group (0/1)
  const int tid = threadIdx.x;
  const int wave = tid >> 6;
  const int lane = tid & 63;
  const int lm = lane & 15;            // batch row (M) / gate-col row (N)
  const int lq = lane >> 4;            // k-quarter within a 32-K tile

  // ---- stage W_ih slice into LDS as bf16 (once) ----
  for (int i = tid; i < 128 * II; i += NT) {
    const int row = i >> 8, k = i & 255;
    const int grow = (row >> 5) * HH + wgj * 32 + (row & 31);
    Wi[row][k] = (__bf16)W_ih[(size_t)grow * II + k];
  }

  // ---- W_hh fragments -> registers: wb[n][kt] (128 VGPR/lane) ----
  bf16x8 wb[8][4];
#pragma unroll
  for (int n = 0; n < 8; ++n) {
    const int localN = n * 16 + lm;
    const int grow = (localN >> 5) * HH + wgj * 32 + (localN & 31);
    const float* whr = W_hh + (size_t)grow * HH + wave * 128 + lq * 8;
#pragma unroll
    for (int kt = 0; kt < 4; ++kt)
      wb[n][kt] = cvt8(*(const float4*)(whr + kt * 32),
                       *(const float4*)(whr + kt * 32 + 4));
  }

  // ---- cell mapping: 256 threads x 2 cells (16 batches x 32 cols) ----
  const int bl = tid >> 4;             // local batch 0..15
  const int cpl = (tid & 15) * 2;      // even local h-col 0..30
  const int gb = grp * 16 + bl;        // global batch
  const int gcol = wgj * 32 + cpl;     // global h-col
  const int rkey = ((bl & 3) ^ ((bl >> 2) & 3)) << 3;   // pgat read swizzle
  const int rcol = cpl ^ rkey;                          // swizzled col base
  float2 cc, hl = make_float2(0.f, 0.f);
  float2 bI = *(const float2*)(b_ih + 0 * HH + gcol);
  float2 bF = *(const float2*)(b_ih + 1 * HH + gcol);
  float2 bG = *(const float2*)(b_ih + 2 * HH + gcol);
  float2 bO = *(const float2*)(b_ih + 3 * HH + gcol);
  cc = *(const float2*)(c0 + gb * HH + gcol);

  // ---- pointers ----
  unsigned* grpb = hw + grp * 2 * SLOTW;
  const char* pl0 = (const char*)(grpb + lm * 512 + wave * 128 + lq * 8);
  const char* pl1 = (const char*)(grpb + SLOTW + lm * 512 + wave * 128 + lq * 8);
  unsigned* pub0 = grpb + bl * 512 + gcol;
  unsigned* pub1 = grpb + SLOTW + bl * 512 + gcol;
  const float* xrow = x + (size_t)(grp * 16 + lm) * (SS * II) + wave * 64 + lq * 8;

  // ---- x pipeline: xa = bf16 frags for step t; xr = raw f32 for t+1 ----
  float4 xr0, xr1, xr2, xr3;
  bf16x8 xa0, xa1;
#define XLOAD(T) { const float* xt_ = xrow + (size_t)(T) * II; \
  xr0 = *(const float4*)(xt_);      xr1 = *(const float4*)(xt_ + 4);  \
  xr2 = *(const float4*)(xt_ + 32); xr3 = *(const float4*)(xt_ + 36); }
#define XCVT() { xa0 = cvt8(xr0, xr1); xa1 = cvt8(xr2, xr3); }
  XLOAD(0) XCVT() XLOAD(1)

  __syncthreads();

#define LDC(Q, OFF) asm volatile( \
  "global_load_dwordx4 %0, %1, off offset:" #OFF " sc0 sc1" \
  : "=v"(Q) : "v"(pbn) : "memory");
#define PULLALL() { \
  LDC(q0, 0)   LDC(q1, 16)  LDC(q2, 128) LDC(q3, 144) \
  LDC(q4, 256) LDC(q5, 272) LDC(q6, 384) LDC(q7, 400) }
#define CK(Q, BIT) { if (((Q.x ^ etag) | (Q.z ^ etag)) & 0xFFFF0000u) \
  st |= BIT##u; }
#define RLD(Q, OFF, BIT) if (__any((int)(st & BIT##u))) { asm volatile( \
  "global_load_dwordx4 %0, %1, off offset:" #OFF " sc0 sc1" \
  : "=v"(Q) : "v"(pb) : "memory"); }
#define HSTEP(QA, QB, KT) { FRG u_; \
  u_.d[0] = __builtin_amdgcn_perm(QA.y, QA.x, 0x05040100u); \
  u_.d[1] = __builtin_amdgcn_perm(QA.w, QA.z, 0x05040100u); \
  u_.d[2] = __builtin_amdgcn_perm(QB.y, QB.x, 0x05040100u); \
  u_.d[3] = __builtin_amdgcn_perm(QB.w, QB.z, 0x05040100u); \
  _Pragma("unroll") \
  for (int n = 0; n < 8; ++n) \
    acc[n] = __builtin_amdgcn_mfma_f32_16x16x32_bf16(u_.b, wb[n][KT], \
                                                     acc[n], 0, 0, 0); }

  u32x4 q0, q1, q2, q3, q4, q5, q6, q7;
  // ---- prologue: pulls for t=0 (slot 0) ----
  { const char* pbn = pl0; PULLALL(); }

  for (int t = 0; t < SS; ++t) {
    const unsigned etag = ((unsigned)t) << 16;
    const char* pb = (t & 1) ? pl1 : pl0;

    // ---- 1. x-part (overlaps pull flight): LDS weights, reg x-frags ----
    f32x4 acc[8] = {};
#pragma unroll
    for (int n = 0; n < 8; ++n) {
      const bf16x8 wib = *(const bf16x8*)(&Wi[n * 16 + lm][wave * 64 + lq * 8]);
      acc[n] = __builtin_amdgcn_mfma_f32_16x16x32_bf16(xa0, wib, acc[n], 0, 0, 0);
    }
#pragma unroll
    for (int n = 0; n < 8; ++n) {
      const bf16x8 wib =
          *(const bf16x8*)(&Wi[n * 16 + lm][wave * 64 + 32 + lq * 8]);
      acc[n] = __builtin_amdgcn_mfma_f32_16x16x32_bf16(xa1, wib, acc[n], 0, 0, 0);
    }

    // ---- 2. spin on data tags, selective per-chunk reload (fan = 16) ----
    for (;;) {
      asm volatile("s_waitcnt vmcnt(0)" ::: "memory");
      __builtin_amdgcn_sched_barrier(0);
      unsigned st = 0u;
      CK(q0, 0x1)  CK(q1, 0x2)  CK(q2, 0x4)  CK(q3, 0x8)
      CK(q4, 0x10) CK(q5, 0x20) CK(q6, 0x40) CK(q7, 0x80)
      if (__all((int)(st == 0u))) break;
      RLD(q0, 0, 0x1)    RLD(q1, 16, 0x2)
      RLD(q2, 128, 0x4)  RLD(q3, 144, 0x8)
      RLD(q4, 256, 0x10) RLD(q5, 272, 0x20)
      RLD(q6, 384, 0x40) RLD(q7, 400, 0x80)
    }

    // ---- 3. x pipeline maintenance at spin-exit: xa <- x(t+1); issue
    //         x(t+2) loads NOW so they are ~1000cy old at the next spin ----
    XCVT()
    { const int tn = (t + 2 < SS) ? t + 2 : SS - 1; XLOAD(tn) }

    // ---- 4. h-part: 4 K-tiles x 8 N-tiles of MFMA (pure reg operands) ----
    HSTEP(q0, q1, 0) HSTEP(q2, q3, 1) HSTEP(q4, q5, 2) HSTEP(q6, q7, 3)

    // ---- 5. per-wave partials -> LDS (parity buffer, XOR-swizzled) ----
    // D layout: col = lane&15 (N), row = lq*4 + r (M) [m89]; key=(r^lq)<<3
    float (*pg)[16][128] = pgat[t & 1];
#pragma unroll
    for (int n = 0; n < 8; ++n)
#pragma unroll
      for (int r = 0; r < 4; ++r)
        pg[wave][lq * 4 + r][(n * 16 + lm) ^ ((r ^ lq) << 3)] = acc[n][r];
    __syncthreads();

    // ---- 6. cell math (2 cells/thread, float2 swizzled reads) ----
    {
      float2 sI = {0.f, 0.f}, sF = {0.f, 0.f}, sG = {0.f, 0.f}, sO = {0.f, 0.f};
#pragma unroll
      for (int w = 0; w < 4; ++w) {
        const float* base = &pg[w][bl][0];
        const float2 a0 = *(const float2*)(base + rcol);
        const float2 a1 = *(const float2*)(base + rcol + 32);
        const float2 a2 = *(const float2*)(base + rcol + 64);
        const float2 a3 = *(const float2*)(base + rcol + 96);
        sI.x += a0.x; sI.y += a0.y; sF.x += a1.x; sF.y += a1.y;
        sG.x += a2.x; sG.y += a2.y; sO.x += a3.x; sO.y += a3.y;
      }
      float hv0, hv1;
      unsigned pw0, pw1;
      const unsigned th = ((unsigned)(t + 1)) << 16;
#pragma unroll
      for (int j = 0; j < 2; ++j) {
        float iv = (j ? sI.y : sI.x) + (j ? bI.y : bI.x);
        float fv = (j ? sF.y : sF.x) + (j ? bF.y : bF.x);
        float gv = (j ? sG.y : sG.x) + (j ? bG.y : bG.x);
        float o  = (j ? sO.y : sO.x) + (j ? bO.y : bO.x);
        iv = __builtin_amdgcn_rcpf(1.f + __expf(-iv));
        fv = __builtin_amdgcn_rcpf(1.f + __expf(-fv));
        o  = __builtin_amdgcn_rcpf(1.f + __expf(-o));
        gv = 2.f * __builtin_amdgcn_rcpf(1.f + __expf(-2.f * gv)) - 1.f;
        float cj = (j ? cc.y : cc.x);
        cj = fv * cj + iv * gv;
        const float thh =
            2.f * __builtin_amdgcn_rcpf(1.f + __expf(-2.f * cj)) - 1.f;
        const float hv = o * thh;
        BFU b_; b_.h = (__bf16)hv;
        if (j) { cc.y = cj; hv1 = hv; pw1 = th | (unsigned)b_.u; }
        else   { cc.x = cj; hv0 = hv; pw0 = th | (unsigned)b_.u; }
      }
      hl.x = hv0; hl.y = hv1;
      u32x2 pv; pv.x = pw0; pv.y = pw1;
      unsigned* pub = (t & 1) ? pub0 : pub1;   // step t -> slot (t+1)&1
      asm volatile("global_store_dwordx2 %0, %1, off sc0 sc1"
                   :: "v"(pub), "v"(pv) : "memory");
      // out[] store after publish: off the critical path
      float2 ov; ov.x = hv0; ov.y = hv1;
      *(float2*)(out + (size_t)gb * (SS * HH) + (size_t)t * HH + gcol) = ov;
    }

    // ---- 7. EARLY PULLS for step t+1: issued right after own publish, so
    //         flight overlaps peers' publish visibility. Tag check at the
    //         next spin rejects any stale catch; peers cannot write tag t+3
    //         into this slot until we publish t+1 (after our spin-exit),
    //         so no ABA and no deadlock. ----
    { const char* pbn = (t & 1) ? pl0 : pl1; PULLALL(); }
    // no trailing barrier: pgat is parity-double-buffered; step t+2 writes
    // require passing the (t+1) barrier, which all step-t readers finished.
  }

  // ---- final h, c ----
  {
    const size_t OUTH = (size_t)BB * SS * HH;
    *(float2*)(out + OUTH + gb * HH + gcol) = hl;
    *(float2*)(out + OUTH + BB * HH + gb * HH + gcol) = cc;
  }
}

extern "C" void kernel_launch(void* const* d_in, const int* in_sizes, int n_in,
                              void* d_out, int out_size, void* d_ws, size_t ws_size,
                              hipStream_t stream) {
  const float* x    = (const float*)d_in[0];
  const float* h0   = (const float*)d_in[1];
  const float* c0   = (const float*)d_in[2];
  const float* W_ih = (const float*)d_in[3];
  const float* b_ih = (const float*)d_in[4];
  const float* W_hh = (const float*)d_in[5];
  float* out = (float*)d_out;

  // ws: tagged h words, 2 groups x 2 slots x 8192 u32 = 128KB. No flags.
  unsigned* hw = (unsigned*)d_ws;

  lstm_init<<<64, 256, 0, stream>>>(h0, hw);
  lstm_persistent<<<32, 256, 0, stream>>>(x, c0, W_ih, b_ih, W_hh, out, hw);
}